// Round 5
// baseline (266.250 us; speedup 1.0000x reference)
//
#include <hip/hip_runtime.h>
#include <stdint.h>
#include <stddef.h>

// Problem: X=2048, Y=256, F=128, H=8, NF=32, O=H*NF=256. f32 I/O, mask int32.
//
// Round 5: occupancy + VALU + LDS-traffic attack.
//  - 1024-thread blocks (16 waves), XPB=8 x's per block, grid 256 (1 block/CU)
//  - wave w = (rg = w>>1, cg = w&1): owns rows [32rg,32rg+32) x cols [128cg,128cg+128)
//    acc[2][8] (64 AGPR) + ah[2][4] f16 (32 VGPR) -> ~128 regs -> 4 waves/SIMD
//  - f16 single-pass MFMA (no hi/lo split): W1/W2 converted once to f16 fragments
//  - LN row stats via lane-butterfly + cross-colgroup LDS exchange
//  - coefT stride 257 to break logit-store bank conflicts

typedef __attribute__((ext_vector_type(8))) _Float16 f16x8;  // 4 VGPRs
typedef __attribute__((ext_vector_type(8))) float f32x8;
typedef __attribute__((ext_vector_type(4))) float f32x4;

#define XPB 8
#define NBLK 256

// dynamic LDS layout (bytes)
#define OFF_W1   0u        // 65536: W1 f16 fragments [ntg*4+kk][l][8], ntg 0..15
#define OFF_W2   65536u    // 4096 : W2 f16 fragments [kk][l][8] (cols 8..15 = 0)
#define OFF_COEF 69632u    // 8224 : float[8][257] logits -> coefs (head-major, padded)
#define OFF_OUTP 77856u    // 8192 : float[16][128] per-wave output partials
#define OFF_SNQ  86048u    // 4096 : float s[256][2], q[256][2] (cg-partial LN stats)
#define OFF_B1   90144u    // 1024 : float[256]
#define OFF_G    91168u    // 1024
#define OFF_BT   92192u    // 1024
#define OFF_B2   93216u    // 64   : float[16]
#define LDS_BYTES 93280u

__device__ __forceinline__ f32x4 mfma16(f16x8 a, f16x8 b, f32x4 c){
  return __builtin_amdgcn_mfma_f32_16x16x32_f16(a, b, c, 0, 0, 0);
}

__global__ __launch_bounds__(1024, 4) void attn_main(
    const float* __restrict__ xy, const int* __restrict__ mask,
    const float* __restrict__ W1g, const float* __restrict__ b1g,
    const float* __restrict__ gammag, const float* __restrict__ betag,
    const float* __restrict__ W2g, const float* __restrict__ b2g,
    float* __restrict__ out)
{
  extern __shared__ char smem[];
  const int tid = threadIdx.x;
  const int l  = tid & 63;
  const int w  = tid >> 6;     // wave 0..15
  const int rg = w >> 1;       // row group 0..7  (rows 32rg..32rg+32)
  const int cg = w & 1;        // col group 0..1  (cols 128cg..128cg+128)
  const int lg = l >> 4;       // lane group 0..3
  const int lc = l & 15;

  _Float16* w1f = (_Float16*)(smem + OFF_W1);
  _Float16* w2f = (_Float16*)(smem + OFF_W2);
  float* coefT = (float*)(smem + OFF_COEF);   // [8][257]
  float* outp  = (float*)(smem + OFF_OUTP);   // [16][128]
  float* snqS  = (float*)(smem + OFF_SNQ);            // [256][2]
  float* snqQ  = (float*)(smem + OFF_SNQ + 2048u);    // [256][2]
  float* ldsB1 = (float*)(smem + OFF_B1);
  float* ldsG  = (float*)(smem + OFF_G);
  float* ldsBt = (float*)(smem + OFF_BT);
  float* ldsB2 = (float*)(smem + OFF_B2);

  if (tid < 256){
    ldsB1[tid] = b1g[tid];
    ldsG[tid]  = gammag[tid];
    ldsBt[tid] = betag[tid];
  }
  if (tid < 16) ldsB2[tid] = (tid < 8) ? b2g[tid] : 0.f;

  // ---- gather W1 (f32) -> f16 fragment order:
  //      idx=((ntg*4+kk)*64+l)*8+j, value=W1[f][o], f=kk*32+(l>>4)*8+j, o=ntg*16+(l&15)
  #pragma unroll
  for (int i = 0; i < 4; ++i){
    int base = i * 8192 + tid * 8;
    int bl  = (base >> 3) & 63;
    int bkk = (base >> 9) & 3;
    int bnt = base >> 11;
    int o   = bnt * 16 + (bl & 15);
    int f0  = bkk * 32 + ((bl >> 4) << 3);
    f16x8 v;
    #pragma unroll
    for (int j = 0; j < 8; ++j) v[j] = (_Float16)W1g[(size_t)(f0 + j) * 256 + o];
    *(f16x8*)(w1f + base) = v;
  }
  // ---- gather W2 -> f16 fragments (pad cols 8..15 with zero) ----
  if (tid < 256){
    int base = tid * 8;
    int bl  = (base >> 3) & 63;
    int bkk = base >> 9;
    int h   = bl & 15;
    int f0  = bkk * 32 + ((bl >> 4) << 3);
    f16x8 v;
    #pragma unroll
    for (int j = 0; j < 8; ++j)
      v[j] = (h < 8) ? (_Float16)W2g[(size_t)(f0 + j) * 8 + h] : (_Float16)0.f;
    *(f16x8*)(w2f + base) = v;
  }

  const int x0 = blockIdx.x * XPB;

  for (int xi = 0; xi < XPB; ++xi){
    const int x = x0 + xi;
    __syncthreads();   // iter0: gathers visible; later: WAR on coefT/outp/snq

    // ---- load A rows, leaky_relu (f32-exact), convert to f16 ----
    f16x8 ah[2][4];
    #pragma unroll
    for (int rt = 0; rt < 2; ++rt)
      #pragma unroll
      for (int kk = 0; kk < 4; ++kk){
        f32x8 v = *(const f32x8*)(xy + (((size_t)x * 256 + rg * 32 + rt * 16 + lc) << 7)
                                     + kk * 32 + (lg << 3));
        f16x8 vh;
        #pragma unroll
        for (int j = 0; j < 8; ++j){
          float f = v[j];
          f = (f >= 0.f) ? f : 0.01f * f;
          vh[j] = (_Float16)f;
        }
        ah[rt][kk] = vh;
      }

    // ---- logits (cg==0 waves): lr @ W2 (padded to 16 cols) ----
    if (cg == 0){
      f32x4 la0 = {0.f,0.f,0.f,0.f}, la1 = {0.f,0.f,0.f,0.f};
      #pragma unroll
      for (int kk = 0; kk < 4; ++kk){
        f16x8 wb = *(const f16x8*)(w2f + (kk * 64 + l) * 8);
        la0 = mfma16(ah[0][kk], wb, la0);
        la1 = mfma16(ah[1][kk], wb, la1);
      }
      if (lc < 8){
        float b2v = ldsB2[lc];
        #pragma unroll
        for (int r = 0; r < 4; ++r){
          int row = rg * 32 + (lg << 2) + r;   // C/D: row=(l>>4)*4+r, col=l&15 (head)
          coefT[lc * 257 + row]      = la0[r] + b2v;
          coefT[lc * 257 + row + 16] = la1[r] + b2v;
        }
      }
    }
    __syncthreads();   // logits visible

    // ---- softmax over Y for head w (waves 0..7; mask-fill logits with 0) ----
    if (w < 8){
      float lgv[4];
      #pragma unroll
      for (int k = 0; k < 4; ++k){
        int y = (k << 6) + l;
        int mk = mask[(x << 8) + y];
        float v = coefT[w * 257 + y];
        lgv[k] = mk ? 0.f : v;
      }
      float mx = fmaxf(fmaxf(lgv[0], lgv[1]), fmaxf(lgv[2], lgv[3]));
      #pragma unroll
      for (int mm = 1; mm < 64; mm <<= 1) mx = fmaxf(mx, __shfl_xor(mx, mm));
      float e[4]; float sum = 0.f;
      #pragma unroll
      for (int k = 0; k < 4; ++k){ e[k] = __expf(lgv[k] - mx); sum += e[k]; }
      #pragma unroll
      for (int mm = 1; mm < 64; mm <<= 1) sum += __shfl_xor(sum, mm);
      float inv = 1.f / sum;
      #pragma unroll
      for (int k = 0; k < 4; ++k) coefT[w * 257 + (k << 6) + l] = e[k] * inv;
    }
    __syncthreads();   // coefs visible

    // ---- GEMM: acc[rt][nt], rows rg*32+rt*16+lg*4+r, col cg*128+nt*16+lc ----
    f32x4 acc[2][8];
    #pragma unroll
    for (int rt = 0; rt < 2; ++rt)
      #pragma unroll
      for (int nt = 0; nt < 8; ++nt)
        acc[rt][nt] = (f32x4){0.f,0.f,0.f,0.f};

    #pragma unroll
    for (int nt = 0; nt < 8; ++nt){
      int ntg = cg * 8 + nt;
      #pragma unroll
      for (int kk = 0; kk < 4; ++kk){
        f16x8 b = *(const f16x8*)(w1f + ((ntg * 4 + kk) * 64 + l) * 8);
        acc[0][nt] = mfma16(ah[0][kk], b, acc[0][nt]);
        acc[1][nt] = mfma16(ah[1][kk], b, acc[1][nt]);
      }
    }

    // ---- += b1, per-colgroup LN partials (butterfly over lc bits 1,2,4,8) ----
    float s[2][4], q[2][4];
    #pragma unroll
    for (int rt = 0; rt < 2; ++rt)
      #pragma unroll
      for (int r = 0; r < 4; ++r){ s[rt][r] = 0.f; q[rt][r] = 0.f; }
    #pragma unroll
    for (int nt = 0; nt < 8; ++nt){
      float bv = ldsB1[cg * 128 + nt * 16 + lc];
      #pragma unroll
      for (int rt = 0; rt < 2; ++rt)
        #pragma unroll
        for (int r = 0; r < 4; ++r){
          float v = acc[rt][nt][r] + bv;
          acc[rt][nt][r] = v;
          s[rt][r] += v;
          q[rt][r] += v * v;
        }
    }
    #pragma unroll
    for (int mm = 1; mm <= 8; mm <<= 1){
      #pragma unroll
      for (int rt = 0; rt < 2; ++rt)
        #pragma unroll
        for (int r = 0; r < 4; ++r){
          s[rt][r] += __shfl_xor(s[rt][r], mm);
          q[rt][r] += __shfl_xor(q[rt][r], mm);
        }
    }
    if (lc == 0){
      #pragma unroll
      for (int rt = 0; rt < 2; ++rt)
        #pragma unroll
        for (int r = 0; r < 4; ++r){
          int row = rg * 32 + rt * 16 + (lg << 2) + r;
          snqS[row * 2 + cg] = s[rt][r];
          snqQ[row * 2 + cg] = q[rt][r];
        }
    }
    __syncthreads();   // both col-groups' partials visible

    // ---- combine stats, LN params per row ----
    float mu[2][4], rstd[2][4];
    #pragma unroll
    for (int rt = 0; rt < 2; ++rt)
      #pragma unroll
      for (int r = 0; r < 4; ++r){
        int row = rg * 32 + rt * 16 + (lg << 2) + r;
        float st = snqS[row * 2] + snqS[row * 2 + 1];
        float qt = snqQ[row * 2] + snqQ[row * 2 + 1];
        float m = st * (1.f / 256.f);
        float var = qt * (1.f / 256.f) - m * m;
        mu[rt][r] = m;
        rstd[rt][r] = rsqrtf(fmaxf(var, 0.f) + 1e-5f);
      }

    // ---- fused LN-affine + coef-weighted sum over this wave's 32 rows ----
    #pragma unroll
    for (int nt = 0; nt < 8; ++nt){
      int col = cg * 128 + nt * 16 + lc;
      int h = col >> 5;
      float gm = ldsG[col], bt = ldsBt[col];
      float c0r[4], c1r[4];
      #pragma unroll
      for (int r = 0; r < 4; ++r){
        c0r[r] = coefT[h * 257 + rg * 32 + (lg << 2) + r];
        c1r[r] = coefT[h * 257 + rg * 32 + 16 + (lg << 2) + r];
      }
      float p = 0.f;
      #pragma unroll
      for (int r = 0; r < 4; ++r){
        float hn0 = (acc[0][nt][r] - mu[0][r]) * rstd[0][r] * gm + bt;
        float hn1 = (acc[1][nt][r] - mu[1][r]) * rstd[1][r] * gm + bt;
        p += c0r[r] * hn0 + c1r[r] * hn1;
      }
      p += __shfl_xor(p, 16);
      p += __shfl_xor(p, 32);
      if (lg == 0) outp[w * 128 + nt * 16 + lc] = p;
    }
    __syncthreads();   // outp partials visible

    // ---- cross-wave reduce (8 row-groups) + f32 store ----
    if (tid < 256){
      int cgc = tid >> 7, idx = tid & 127;
      float sum = 0.f;
      #pragma unroll
      for (int r8 = 0; r8 < 8; ++r8) sum += outp[(r8 * 2 + cgc) * 128 + idx];
      out[((size_t)x << 8) + tid] = sum;
    }
  }
}

extern "C" void kernel_launch(void* const* d_in, const int* in_sizes, int n_in,
                              void* d_out, int out_size, void* d_ws, size_t ws_size,
                              hipStream_t stream){
  (void)in_sizes; (void)n_in; (void)out_size; (void)d_ws; (void)ws_size;
  const float* xy    = (const float*)d_in[0];
  const int*   mask  = (const int*)d_in[1];
  const float* W1    = (const float*)d_in[2];
  const float* b1    = (const float*)d_in[3];
  const float* gamma = (const float*)d_in[4];
  const float* beta  = (const float*)d_in[5];
  const float* W2    = (const float*)d_in[6];
  const float* b2    = (const float*)d_in[7];

  hipFuncSetAttribute((const void*)attn_main,
                      hipFuncAttributeMaxDynamicSharedMemorySize, (int)LDS_BYTES);
  attn_main<<<NBLK, 1024, LDS_BYTES, stream>>>(xy, mask, W1, b1, gamma, beta, W2, b2,
                                               (float*)d_out);
}

// Round 6
// 179.784 us; speedup vs baseline: 1.4809x; 1.4809x over previous
//
#include <hip/hip_runtime.h>
#include <stdint.h>
#include <stddef.h>

// Problem: X=2048, Y=256, F=128, H=8, NF=32, O=H*NF=256. f32 I/O, mask int32.
//
// Round 6 = round-4 structure (512 thr, 8 waves, wave w owns rows [32w,32w+32),
// all 256 cols, XPB=8, grid 256) with:
//  - f16 single-pass MFMA (W1/W2 -> f16 fragments once per block)
//  - A register prefetch across xi (araw f32, converted to f16+leaky at use)
//  - softmax overlapped under GEMM (no barrier between softmax and GEMM)
//  - mask prefetched to registers at iteration top
//  - coefT padded stride 257 (bank conflicts)
//  - algebraic epilogue: out = gamma * sum_y c*rstd*(hid-mu) + beta

typedef __attribute__((ext_vector_type(8))) _Float16 f16x8;  // 4 VGPRs
typedef __attribute__((ext_vector_type(8))) float f32x8;
typedef __attribute__((ext_vector_type(4))) float f32x4;

#define XPB 8
#define NBLK 256

// dynamic LDS layout (bytes)
#define OFF_W1   0u        // 65536: W1 f16 fragments [(nt*4+kk)][l][8]
#define OFF_W2   65536u    // 4096 : W2 f16 fragments [kk][l][8] (cols 8..15 = 0)
#define OFF_COEF 69632u    // 8224 : float[8][257] logits -> coefs (head-major, padded)
#define OFF_OUTP 77856u    // 8192 : float[8][256] per-wave output partials
#define OFF_B1   86048u    // 1024 : float[256]
#define OFF_G    87072u    // 1024
#define OFF_BT   88096u    // 1024
#define OFF_B2   89120u    // 64   : float[16]
#define LDS_BYTES 89184u

__device__ __forceinline__ f32x4 mfma16(f16x8 a, f16x8 b, f32x4 c){
  return __builtin_amdgcn_mfma_f32_16x16x32_f16(a, b, c, 0, 0, 0);
}

__global__ __launch_bounds__(512, 2) void attn_main(
    const float* __restrict__ xy, const int* __restrict__ mask,
    const float* __restrict__ W1g, const float* __restrict__ b1g,
    const float* __restrict__ gammag, const float* __restrict__ betag,
    const float* __restrict__ W2g, const float* __restrict__ b2g,
    float* __restrict__ out)
{
  extern __shared__ char smem[];
  const int tid = threadIdx.x;
  const int l  = tid & 63;
  const int w  = tid >> 6;     // wave 0..7; owns rows [32w, 32w+32)
  const int lg = l >> 4;       // lane group 0..3
  const int lc = l & 15;

  _Float16* w1f = (_Float16*)(smem + OFF_W1);
  _Float16* w2f = (_Float16*)(smem + OFF_W2);
  float* coefT = (float*)(smem + OFF_COEF);   // [8][257]
  float* outp  = (float*)(smem + OFF_OUTP);   // [8][256]
  float* ldsB1 = (float*)(smem + OFF_B1);
  float* ldsG  = (float*)(smem + OFF_G);
  float* ldsBt = (float*)(smem + OFF_BT);
  float* ldsB2 = (float*)(smem + OFF_B2);

  if (tid < 256){
    ldsB1[tid] = b1g[tid];
    ldsG[tid]  = gammag[tid];
    ldsBt[tid] = betag[tid];
  }
  if (tid < 16) ldsB2[tid] = (tid < 8) ? b2g[tid] : 0.f;

  // ---- gather W1 (f32) -> f16 fragment order:
  //      idx=((nt*4+kk)*64+l)*8+j, value=W1[f][o], f=kk*32+(l>>4)*8+j, o=nt*16+(l&15)
  #pragma unroll
  for (int i = 0; i < 8; ++i){
    int base = i * 4096 + tid * 8;
    int bl  = (base >> 3) & 63;
    int bkk = (base >> 9) & 3;
    int bnt = base >> 11;
    int o   = bnt * 16 + (bl & 15);
    int f0  = bkk * 32 + ((bl >> 4) << 3);
    f16x8 v;
    #pragma unroll
    for (int j = 0; j < 8; ++j) v[j] = (_Float16)W1g[(size_t)(f0 + j) * 256 + o];
    *(f16x8*)(w1f + base) = v;
  }
  // ---- gather W2 -> f16 fragments (pad cols 8..15 with zero) ----
  if (tid < 256){
    int base = tid * 8;
    int bl  = (base >> 3) & 63;
    int bkk = base >> 9;
    int h   = bl & 15;
    int f0  = bkk * 32 + ((bl >> 4) << 3);
    f16x8 v;
    #pragma unroll
    for (int j = 0; j < 8; ++j)
      v[j] = (h < 8) ? (_Float16)W2g[(size_t)(f0 + j) * 8 + h] : (_Float16)0.f;
    *(f16x8*)(w2f + base) = v;
  }

  const int x0 = blockIdx.x * XPB;

  // register prefetch of first x's A rows (raw f32)
  f32x8 araw[2][4];
  #pragma unroll
  for (int rt = 0; rt < 2; ++rt)
    #pragma unroll
    for (int kk = 0; kk < 4; ++kk)
      araw[rt][kk] = *(const f32x8*)(xy + (((size_t)x0 * 256 + w * 32 + rt * 16 + lc) << 7)
                                        + kk * 32 + (lg << 3));

  for (int xi = 0; xi < XPB; ++xi){
    const int x = x0 + xi;
    __syncthreads();   // iter0: gathers visible; later: WAR on coefT/outp

    // ---- prefetch mask for current x (hidden under convert+logits) ----
    int mk[4];
    #pragma unroll
    for (int k = 0; k < 4; ++k) mk[k] = mask[(x << 8) + (k << 6) + l];

    // ---- leaky_relu (f32-exact) + convert to f16 ----
    f16x8 ah[2][4];
    #pragma unroll
    for (int rt = 0; rt < 2; ++rt)
      #pragma unroll
      for (int kk = 0; kk < 4; ++kk){
        f32x8 v = araw[rt][kk];
        f16x8 vh;
        #pragma unroll
        for (int j = 0; j < 8; ++j){
          float f = v[j];
          f = (f >= 0.f) ? f : 0.01f * f;
          vh[j] = (_Float16)f;
        }
        ah[rt][kk] = vh;
      }

    // ---- prefetch next x's A rows (in flight across logits/softmax/GEMM) ----
    if (xi + 1 < XPB){
      #pragma unroll
      for (int rt = 0; rt < 2; ++rt)
        #pragma unroll
        for (int kk = 0; kk < 4; ++kk)
          araw[rt][kk] = *(const f32x8*)(xy + (((size_t)(x + 1) * 256 + w * 32 + rt * 16 + lc) << 7)
                                            + kk * 32 + (lg << 3));
    }

    // ---- logits: lr @ W2 (padded to 16 cols), 8 MFMA ----
    {
      f32x4 la0 = {0.f,0.f,0.f,0.f}, la1 = {0.f,0.f,0.f,0.f};
      #pragma unroll
      for (int kk = 0; kk < 4; ++kk){
        f16x8 wb = *(const f16x8*)(w2f + (kk * 64 + l) * 8);
        la0 = mfma16(ah[0][kk], wb, la0);
        la1 = mfma16(ah[1][kk], wb, la1);
      }
      if (lc < 8){
        float b2v = ldsB2[lc];
        #pragma unroll
        for (int r = 0; r < 4; ++r){
          int row = (w << 5) + (lg << 2) + r;   // C/D: row=(l>>4)*4+r, col=l&15 (head)
          coefT[lc * 257 + row]      = la0[r] + b2v;
          coefT[lc * 257 + row + 16] = la1[r] + b2v;
        }
      }
    }
    __syncthreads();   // all logits visible

    // ---- softmax over Y for head w (mask-fill logits with 0 per reference);
    //      GEMM below does not depend on it -> its latency hides under MFMA ----
    {
      float lgv[4];
      #pragma unroll
      for (int k = 0; k < 4; ++k){
        float v = coefT[w * 257 + (k << 6) + l];
        lgv[k] = mk[k] ? 0.f : v;
      }
      float mx = fmaxf(fmaxf(lgv[0], lgv[1]), fmaxf(lgv[2], lgv[3]));
      #pragma unroll
      for (int mm = 1; mm < 64; mm <<= 1) mx = fmaxf(mx, __shfl_xor(mx, mm));
      float e[4]; float sum = 0.f;
      #pragma unroll
      for (int k = 0; k < 4; ++k){ e[k] = __expf(lgv[k] - mx); sum += e[k]; }
      #pragma unroll
      for (int mm = 1; mm < 64; mm <<= 1) sum += __shfl_xor(sum, mm);
      float inv = 1.f / sum;
      #pragma unroll
      for (int k = 0; k < 4; ++k) coefT[w * 257 + (k << 6) + l] = e[k] * inv;
    }

    // ---- main GEMM: acc[rt][nt], rows w*32+rt*16+lg*4+r, col nt*16+lc ----
    f32x4 acc[2][16];
    #pragma unroll
    for (int rt = 0; rt < 2; ++rt)
      #pragma unroll
      for (int nt = 0; nt < 16; ++nt)
        acc[rt][nt] = (f32x4){0.f,0.f,0.f,0.f};

    #pragma unroll
    for (int nt = 0; nt < 16; ++nt){
      #pragma unroll
      for (int kk = 0; kk < 4; ++kk){
        f16x8 b = *(const f16x8*)(w1f + ((nt * 4 + kk) * 64 + l) * 8);
        acc[0][nt] = mfma16(ah[0][kk], b, acc[0][nt]);
        acc[1][nt] = mfma16(ah[1][kk], b, acc[1][nt]);
      }
    }
    __syncthreads();   // coefs (softmax writes) visible; acc is register-local

    // ---- hid = acc + b1; LN stats (butterfly over lc bits 1,2,4,8) ----
    float s[2][4], q[2][4];
    #pragma unroll
    for (int rt = 0; rt < 2; ++rt)
      #pragma unroll
      for (int r = 0; r < 4; ++r){ s[rt][r] = 0.f; q[rt][r] = 0.f; }
    #pragma unroll
    for (int nt = 0; nt < 16; ++nt){
      float bv = ldsB1[nt * 16 + lc];
      #pragma unroll
      for (int rt = 0; rt < 2; ++rt)
        #pragma unroll
        for (int r = 0; r < 4; ++r){
          float v = acc[rt][nt][r] + bv;
          acc[rt][nt][r] = v;
          s[rt][r] += v;
          q[rt][r] += v * v;
        }
    }
    #pragma unroll
    for (int mm = 1; mm <= 8; mm <<= 1){
      #pragma unroll
      for (int rt = 0; rt < 2; ++rt)
        #pragma unroll
        for (int r = 0; r < 4; ++r){
          s[rt][r] += __shfl_xor(s[rt][r], mm);
          q[rt][r] += __shfl_xor(q[rt][r], mm);
        }
    }
    float mu[2][4], rstd[2][4];
    #pragma unroll
    for (int rt = 0; rt < 2; ++rt)
      #pragma unroll
      for (int r = 0; r < 4; ++r){
        float m = s[rt][r] * (1.f / 256.f);
        float var = q[rt][r] * (1.f / 256.f) - m * m;
        mu[rt][r] = m;
        rstd[rt][r] = rsqrtf(fmaxf(var, 0.f) + 1e-5f);
      }

    // ---- algebraic contraction: partial[o] = sum_rows c2*(hid - mu),
    //      c2 = coef*rstd; gamma/beta applied at the final reduce ----
    #pragma unroll
    for (int h = 0; h < 8; ++h){
      float c2[2][4];
      float Dl = 0.f;
      #pragma unroll
      for (int rt = 0; rt < 2; ++rt)
        #pragma unroll
        for (int r = 0; r < 4; ++r){
          float c = coefT[h * 257 + (w << 5) + rt * 16 + (lg << 2) + r];
          float v = c * rstd[rt][r];
          c2[rt][r] = v;
          Dl += v * mu[rt][r];
        }
      #pragma unroll
      for (int t = 0; t < 2; ++t){
        int nt = h * 2 + t;               // cols nt*16+lc belong to head nt>>1 == h
        float p = -Dl;
        #pragma unroll
        for (int rt = 0; rt < 2; ++rt)
          #pragma unroll
          for (int r = 0; r < 4; ++r)
            p += c2[rt][r] * acc[rt][nt][r];
        p += __shfl_xor(p, 16);
        p += __shfl_xor(p, 32);
        if (lg == 0) outp[w * 256 + nt * 16 + lc] = p;
      }
    }
    __syncthreads();   // outp partials visible

    // ---- cross-wave reduce, apply gamma/beta, f32 store ----
    if (tid < 256){
      float S = 0.f;
      #pragma unroll
      for (int ww = 0; ww < 8; ++ww) S += outp[ww * 256 + tid];
      out[((size_t)x << 8) + tid] = ldsG[tid] * S + ldsBt[tid];
    }
  }
}

extern "C" void kernel_launch(void* const* d_in, const int* in_sizes, int n_in,
                              void* d_out, int out_size, void* d_ws, size_t ws_size,
                              hipStream_t stream){
  (void)in_sizes; (void)n_in; (void)out_size; (void)d_ws; (void)ws_size;
  const float* xy    = (const float*)d_in[0];
  const int*   mask  = (const int*)d_in[1];
  const float* W1    = (const float*)d_in[2];
  const float* b1    = (const float*)d_in[3];
  const float* gamma = (const float*)d_in[4];
  const float* beta  = (const float*)d_in[5];
  const float* W2    = (const float*)d_in[6];
  const float* b2    = (const float*)d_in[7];

  hipFuncSetAttribute((const void*)attn_main,
                      hipFuncAttributeMaxDynamicSharedMemorySize, (int)LDS_BYTES);
  attn_main<<<NBLK, 512, LDS_BYTES, stream>>>(xy, mask, W1, b1, gamma, beta, W2, b2,
                                              (float*)d_out);
}

// Round 7
// 142.188 us; speedup vs baseline: 1.8725x; 1.2644x over previous
//
#include <hip/hip_runtime.h>
#include <stdint.h>
#include <stddef.h>

// Problem: X=2048, Y=256, F=128, H=8, NF=32, O=H*NF=256. f32 I/O, mask int32.
//
// Round 7 = round 6 minus the spill: A-loads are iteration-scoped, issued
// BEFORE the top barrier (latency absorbed by barrier convergence), dead
// after the f16 convert. Peak reg pressure ~190 < 256 (no scratch).
//  - f16 single-pass MFMA (W1/W2 -> f16 fragments once per block)
//  - softmax overlapped under GEMM
//  - coefT stride 257; algebraic epilogue (gamma/beta folded to final store)

typedef __attribute__((ext_vector_type(8))) _Float16 f16x8;  // 4 VGPRs
typedef __attribute__((ext_vector_type(8))) float f32x8;
typedef __attribute__((ext_vector_type(4))) float f32x4;

#define XPB 8
#define NBLK 256

// dynamic LDS layout (bytes)
#define OFF_W1   0u        // 65536: W1 f16 fragments [(nt*4+kk)][l][8]
#define OFF_W2   65536u    // 4096 : W2 f16 fragments [kk][l][8] (cols 8..15 = 0)
#define OFF_COEF 69632u    // 8224 : float[8][257] logits -> coefs (head-major, padded)
#define OFF_OUTP 77856u    // 8192 : float[8][256] per-wave output partials
#define OFF_B1   86048u    // 1024 : float[256]
#define OFF_G    87072u    // 1024
#define OFF_BT   88096u    // 1024
#define OFF_B2   89120u    // 64   : float[16]
#define LDS_BYTES 89184u

__device__ __forceinline__ f32x4 mfma16(f16x8 a, f16x8 b, f32x4 c){
  return __builtin_amdgcn_mfma_f32_16x16x32_f16(a, b, c, 0, 0, 0);
}

__global__ __launch_bounds__(512, 2) void attn_main(
    const float* __restrict__ xy, const int* __restrict__ mask,
    const float* __restrict__ W1g, const float* __restrict__ b1g,
    const float* __restrict__ gammag, const float* __restrict__ betag,
    const float* __restrict__ W2g, const float* __restrict__ b2g,
    float* __restrict__ out)
{
  extern __shared__ char smem[];
  const int tid = threadIdx.x;
  const int l  = tid & 63;
  const int w  = tid >> 6;     // wave 0..7; owns rows [32w, 32w+32)
  const int lg = l >> 4;       // lane group 0..3
  const int lc = l & 15;

  _Float16* w1f = (_Float16*)(smem + OFF_W1);
  _Float16* w2f = (_Float16*)(smem + OFF_W2);
  float* coefT = (float*)(smem + OFF_COEF);   // [8][257]
  float* outp  = (float*)(smem + OFF_OUTP);   // [8][256]
  float* ldsB1 = (float*)(smem + OFF_B1);
  float* ldsG  = (float*)(smem + OFF_G);
  float* ldsBt = (float*)(smem + OFF_BT);
  float* ldsB2 = (float*)(smem + OFF_B2);

  if (tid < 256){
    ldsB1[tid] = b1g[tid];
    ldsG[tid]  = gammag[tid];
    ldsBt[tid] = betag[tid];
  }
  if (tid < 16) ldsB2[tid] = (tid < 8) ? b2g[tid] : 0.f;

  // ---- gather W1 (f32) -> f16 fragment order:
  //      idx=((nt*4+kk)*64+l)*8+j, value=W1[f][o], f=kk*32+(l>>4)*8+j, o=nt*16+(l&15)
  #pragma unroll
  for (int i = 0; i < 8; ++i){
    int base = i * 4096 + tid * 8;
    int bl  = (base >> 3) & 63;
    int bkk = (base >> 9) & 3;
    int bnt = base >> 11;
    int o   = bnt * 16 + (bl & 15);
    int f0  = bkk * 32 + ((bl >> 4) << 3);
    f16x8 v;
    #pragma unroll
    for (int j = 0; j < 8; ++j) v[j] = (_Float16)W1g[(size_t)(f0 + j) * 256 + o];
    *(f16x8*)(w1f + base) = v;
  }
  // ---- gather W2 -> f16 fragments (pad cols 8..15 with zero) ----
  if (tid < 256){
    int base = tid * 8;
    int bl  = (base >> 3) & 63;
    int bkk = base >> 9;
    int h   = bl & 15;
    int f0  = bkk * 32 + ((bl >> 4) << 3);
    f16x8 v;
    #pragma unroll
    for (int j = 0; j < 8; ++j)
      v[j] = (h < 8) ? (_Float16)W2g[(size_t)(f0 + j) * 8 + h] : (_Float16)0.f;
    *(f16x8*)(w2f + base) = v;
  }

  const int x0 = blockIdx.x * XPB;

  for (int xi = 0; xi < XPB; ++xi){
    const int x = x0 + xi;

    // ---- issue A + mask loads BEFORE the barrier (latency hides under
    //      barrier convergence; regs die right after the convert) ----
    f32x8 araw[2][4];
    #pragma unroll
    for (int rt = 0; rt < 2; ++rt)
      #pragma unroll
      for (int kk = 0; kk < 4; ++kk)
        araw[rt][kk] = *(const f32x8*)(xy + (((size_t)x * 256 + w * 32 + rt * 16 + lc) << 7)
                                          + kk * 32 + (lg << 3));
    int mk[4];
    #pragma unroll
    for (int k = 0; k < 4; ++k) mk[k] = mask[(x << 8) + (k << 6) + l];

    __syncthreads();   // iter0: gathers visible; later: WAR on coefT/outp

    // ---- leaky_relu (f32-exact) + convert to f16 ----
    f16x8 ah[2][4];
    #pragma unroll
    for (int rt = 0; rt < 2; ++rt)
      #pragma unroll
      for (int kk = 0; kk < 4; ++kk){
        f32x8 v = araw[rt][kk];
        f16x8 vh;
        #pragma unroll
        for (int j = 0; j < 8; ++j){
          float f = v[j];
          f = (f >= 0.f) ? f : 0.01f * f;
          vh[j] = (_Float16)f;
        }
        ah[rt][kk] = vh;
      }

    // ---- logits: lr @ W2 (padded to 16 cols), 8 MFMA ----
    {
      f32x4 la0 = {0.f,0.f,0.f,0.f}, la1 = {0.f,0.f,0.f,0.f};
      #pragma unroll
      for (int kk = 0; kk < 4; ++kk){
        f16x8 wb = *(const f16x8*)(w2f + (kk * 64 + l) * 8);
        la0 = mfma16(ah[0][kk], wb, la0);
        la1 = mfma16(ah[1][kk], wb, la1);
      }
      if (lc < 8){
        float b2v = ldsB2[lc];
        #pragma unroll
        for (int r = 0; r < 4; ++r){
          int row = (w << 5) + (lg << 2) + r;   // C/D: row=(l>>4)*4+r, col=l&15 (head)
          coefT[lc * 257 + row]      = la0[r] + b2v;
          coefT[lc * 257 + row + 16] = la1[r] + b2v;
        }
      }
    }
    __syncthreads();   // all logits visible

    // ---- softmax over Y for head w (mask-fill logits with 0 per reference);
    //      GEMM below does not depend on it -> latency hides under MFMA ----
    {
      float lgv[4];
      #pragma unroll
      for (int k = 0; k < 4; ++k){
        float v = coefT[w * 257 + (k << 6) + l];
        lgv[k] = mk[k] ? 0.f : v;
      }
      float mx = fmaxf(fmaxf(lgv[0], lgv[1]), fmaxf(lgv[2], lgv[3]));
      #pragma unroll
      for (int mm = 1; mm < 64; mm <<= 1) mx = fmaxf(mx, __shfl_xor(mx, mm));
      float e[4]; float sum = 0.f;
      #pragma unroll
      for (int k = 0; k < 4; ++k){ e[k] = __expf(lgv[k] - mx); sum += e[k]; }
      #pragma unroll
      for (int mm = 1; mm < 64; mm <<= 1) sum += __shfl_xor(sum, mm);
      float inv = 1.f / sum;
      #pragma unroll
      for (int k = 0; k < 4; ++k) coefT[w * 257 + (k << 6) + l] = e[k] * inv;
    }

    // ---- main GEMM: acc[rt][nt], rows w*32+rt*16+lg*4+r, col nt*16+lc ----
    f32x4 acc[2][16];
    #pragma unroll
    for (int rt = 0; rt < 2; ++rt)
      #pragma unroll
      for (int nt = 0; nt < 16; ++nt)
        acc[rt][nt] = (f32x4){0.f,0.f,0.f,0.f};

    #pragma unroll
    for (int nt = 0; nt < 16; ++nt){
      #pragma unroll
      for (int kk = 0; kk < 4; ++kk){
        f16x8 b = *(const f16x8*)(w1f + ((nt * 4 + kk) * 64 + l) * 8);
        acc[0][nt] = mfma16(ah[0][kk], b, acc[0][nt]);
        acc[1][nt] = mfma16(ah[1][kk], b, acc[1][nt]);
      }
    }
    __syncthreads();   // softmax writes (all waves) visible; acc register-local

    // ---- hid = acc + b1; LN stats (butterfly over lc bits 1,2,4,8) ----
    float s[2][4], q[2][4];
    #pragma unroll
    for (int rt = 0; rt < 2; ++rt)
      #pragma unroll
      for (int r = 0; r < 4; ++r){ s[rt][r] = 0.f; q[rt][r] = 0.f; }
    #pragma unroll
    for (int nt = 0; nt < 16; ++nt){
      float bv = ldsB1[nt * 16 + lc];
      #pragma unroll
      for (int rt = 0; rt < 2; ++rt)
        #pragma unroll
        for (int r = 0; r < 4; ++r){
          float v = acc[rt][nt][r] + bv;
          acc[rt][nt][r] = v;
          s[rt][r] += v;
          q[rt][r] += v * v;
        }
    }
    #pragma unroll
    for (int mm = 1; mm <= 8; mm <<= 1){
      #pragma unroll
      for (int rt = 0; rt < 2; ++rt)
        #pragma unroll
        for (int r = 0; r < 4; ++r){
          s[rt][r] += __shfl_xor(s[rt][r], mm);
          q[rt][r] += __shfl_xor(q[rt][r], mm);
        }
    }
    float mu[2][4], rstd[2][4];
    #pragma unroll
    for (int rt = 0; rt < 2; ++rt)
      #pragma unroll
      for (int r = 0; r < 4; ++r){
        float m = s[rt][r] * (1.f / 256.f);
        float var = q[rt][r] * (1.f / 256.f) - m * m;
        mu[rt][r] = m;
        rstd[rt][r] = rsqrtf(fmaxf(var, 0.f) + 1e-5f);
      }

    // ---- algebraic contraction: partial[o] = sum_rows c2*(hid - mu),
    //      c2 = coef*rstd; gamma/beta applied at the final reduce ----
    #pragma unroll
    for (int h = 0; h < 8; ++h){
      float c2[2][4];
      float Dl = 0.f;
      #pragma unroll
      for (int rt = 0; rt < 2; ++rt)
        #pragma unroll
        for (int r = 0; r < 4; ++r){
          float c = coefT[h * 257 + (w << 5) + rt * 16 + (lg << 2) + r];
          float v = c * rstd[rt][r];
          c2[rt][r] = v;
          Dl += v * mu[rt][r];
        }
      #pragma unroll
      for (int t = 0; t < 2; ++t){
        int nt = h * 2 + t;               // cols nt*16+lc belong to head nt>>1 == h
        float p = -Dl;
        #pragma unroll
        for (int rt = 0; rt < 2; ++rt)
          #pragma unroll
          for (int r = 0; r < 4; ++r)
            p += c2[rt][r] * acc[rt][nt][r];
        p += __shfl_xor(p, 16);
        p += __shfl_xor(p, 32);
        if (lg == 0) outp[w * 256 + nt * 16 + lc] = p;
      }
    }
    __syncthreads();   // outp partials visible

    // ---- cross-wave reduce, apply gamma/beta, f32 store ----
    if (tid < 256){
      float S = 0.f;
      #pragma unroll
      for (int ww = 0; ww < 8; ++ww) S += outp[ww * 256 + tid];
      out[((size_t)x << 8) + tid] = ldsG[tid] * S + ldsBt[tid];
    }
  }
}

extern "C" void kernel_launch(void* const* d_in, const int* in_sizes, int n_in,
                              void* d_out, int out_size, void* d_ws, size_t ws_size,
                              hipStream_t stream){
  (void)in_sizes; (void)n_in; (void)out_size; (void)d_ws; (void)ws_size;
  const float* xy    = (const float*)d_in[0];
  const int*   mask  = (const int*)d_in[1];
  const float* W1    = (const float*)d_in[2];
  const float* b1    = (const float*)d_in[3];
  const float* gamma = (const float*)d_in[4];
  const float* beta  = (const float*)d_in[5];
  const float* W2    = (const float*)d_in[6];
  const float* b2    = (const float*)d_in[7];

  hipFuncSetAttribute((const void*)attn_main,
                      hipFuncAttributeMaxDynamicSharedMemorySize, (int)LDS_BYTES);
  attn_main<<<NBLK, 512, LDS_BYTES, stream>>>(xy, mask, W1, b1, gamma, beta, W2, b2,
                                              (float*)d_out);
}

// Round 8
// 101.230 us; speedup vs baseline: 2.6302x; 1.4046x over previous
//
#include <hip/hip_runtime.h>
#include <stdint.h>
#include <stddef.h>

// Problem: X=2048, Y=256, F=128, H=8, NF=32, O=H*NF=256. f32 I/O, mask int32.
//
// Round 8: occupancy via per-wave state halving.
//  - 1024-thread block (16 waves), wave w owns rows [16w,16w+16) x all 256 cols
//    acc[16] = 64 regs, ah[4] = 16 regs, peak ~95 < 128-reg cap of a 16-wave
//    block (512 wave-regs/SIMD pool) -> 4 waves/SIMD, no spill (verify WRITE_SIZE!)
//  - one x per iteration, XPB=8, grid 256 (1 block/CU)
//  - 3 barriers/iter: logits->softmax, softmax->contraction (GEMM+stats hide it),
//    outp->reduce. Top-of-loop barrier removed (hazards separated by B1..B3).
//  - f16 single-pass MFMA; algebraic epilogue (gamma/beta folded into final store)

typedef __attribute__((ext_vector_type(8))) _Float16 f16x8;  // 4 VGPRs
typedef __attribute__((ext_vector_type(8))) float f32x8;
typedef __attribute__((ext_vector_type(4))) float f32x4;

#define XPB 8
#define NBLK 256

// dynamic LDS layout (bytes)
#define OFF_W1   0u        // 65536: W1 f16 fragments [(nt*4+kk)][l][8]
#define OFF_W2   65536u    // 4096 : W2 f16 fragments [kk][l][8] (cols 8..15 = 0)
#define OFF_COEF 69632u    // 8224 : float[8][257] logits -> coefs (head-major, padded)
#define OFF_OUTP 77856u    // 16384: float[16][256] per-wave output partials
#define OFF_B1   94240u    // 1024 : float[256]
#define OFF_G    95264u    // 1024
#define OFF_BT   96288u    // 1024
#define OFF_B2   97312u    // 64   : float[16]
#define LDS_BYTES 97376u

__device__ __forceinline__ f32x4 mfma16(f16x8 a, f16x8 b, f32x4 c){
  return __builtin_amdgcn_mfma_f32_16x16x32_f16(a, b, c, 0, 0, 0);
}

__global__ __launch_bounds__(1024, 4) void attn_main(
    const float* __restrict__ xy, const int* __restrict__ mask,
    const float* __restrict__ W1g, const float* __restrict__ b1g,
    const float* __restrict__ gammag, const float* __restrict__ betag,
    const float* __restrict__ W2g, const float* __restrict__ b2g,
    float* __restrict__ out)
{
  extern __shared__ char smem[];
  const int tid = threadIdx.x;
  const int l  = tid & 63;
  const int w  = tid >> 6;     // wave 0..15; owns rows [16w, 16w+16)
  const int lg = l >> 4;       // lane group 0..3
  const int lc = l & 15;

  _Float16* w1f = (_Float16*)(smem + OFF_W1);
  _Float16* w2f = (_Float16*)(smem + OFF_W2);
  float* coefT = (float*)(smem + OFF_COEF);   // [8][257]
  float* outp  = (float*)(smem + OFF_OUTP);   // [16][256]
  float* ldsB1 = (float*)(smem + OFF_B1);
  float* ldsG  = (float*)(smem + OFF_G);
  float* ldsBt = (float*)(smem + OFF_BT);
  float* ldsB2 = (float*)(smem + OFF_B2);

  if (tid < 256){
    ldsB1[tid] = b1g[tid];
    ldsG[tid]  = gammag[tid];
    ldsBt[tid] = betag[tid];
  }
  if (tid < 16) ldsB2[tid] = (tid < 8) ? b2g[tid] : 0.f;

  // ---- gather W1 (f32) -> f16 fragment order (1024 threads, 4 rounds):
  //      idx=((nt*4+kk)*64+l)*8+j, value=W1[f][o], f=kk*32+(l>>4)*8+j, o=nt*16+(l&15)
  #pragma unroll
  for (int i = 0; i < 4; ++i){
    int base = i * 8192 + tid * 8;
    int bl  = (base >> 3) & 63;
    int bkk = (base >> 9) & 3;
    int bnt = base >> 11;
    int o   = bnt * 16 + (bl & 15);
    int f0  = bkk * 32 + ((bl >> 4) << 3);
    f16x8 v;
    #pragma unroll
    for (int j = 0; j < 8; ++j) v[j] = (_Float16)W1g[(size_t)(f0 + j) * 256 + o];
    *(f16x8*)(w1f + base) = v;
  }
  // ---- gather W2 -> f16 fragments (pad cols 8..15 with zero) ----
  if (tid < 256){
    int base = tid * 8;
    int bl  = (base >> 3) & 63;
    int bkk = base >> 9;
    int h   = bl & 15;
    int f0  = bkk * 32 + ((bl >> 4) << 3);
    f16x8 v;
    #pragma unroll
    for (int j = 0; j < 8; ++j)
      v[j] = (h < 8) ? (_Float16)W2g[(size_t)(f0 + j) * 8 + h] : (_Float16)0.f;
    *(f16x8*)(w2f + base) = v;
  }
  __syncthreads();   // gathers + params visible

  const int x0 = blockIdx.x * XPB;

  for (int xi = 0; xi < XPB; ++xi){
    const int x = x0 + xi;

    // ---- A rows for this wave (dies right after convert) + mask (waves 0-7) ----
    f32x8 araw[4];
    #pragma unroll
    for (int kk = 0; kk < 4; ++kk)
      araw[kk] = *(const f32x8*)(xy + (((size_t)x * 256 + w * 16 + lc) << 7)
                                    + kk * 32 + (lg << 3));
    int mk[4];
    if (w < 8){
      #pragma unroll
      for (int k = 0; k < 4; ++k) mk[k] = mask[(x << 8) + (k << 6) + l];
    }

    // ---- leaky_relu (f32-exact) + convert to f16 ----
    f16x8 ah[4];
    #pragma unroll
    for (int kk = 0; kk < 4; ++kk){
      f32x8 v = araw[kk];
      f16x8 vh;
      #pragma unroll
      for (int j = 0; j < 8; ++j){
        float f = fmaxf(v[j], 0.f) + 0.01f * fminf(v[j], 0.f);
        vh[j] = (_Float16)f;
      }
      ah[kk] = vh;
    }

    // ---- logits: lr @ W2 (padded to 16 cols), 4 MFMA ----
    {
      f32x4 la = {0.f,0.f,0.f,0.f};
      #pragma unroll
      for (int kk = 0; kk < 4; ++kk){
        f16x8 wb = *(const f16x8*)(w2f + (kk * 64 + l) * 8);
        la = mfma16(ah[kk], wb, la);
      }
      if (lc < 8){
        float b2v = ldsB2[lc];
        #pragma unroll
        for (int r = 0; r < 4; ++r){
          int row = (w << 4) + (lg << 2) + r;   // C/D: row=(l>>4)*4+r, col=l&15 (head)
          coefT[lc * 257 + row] = la[r] + b2v;
        }
      }
    }
    __syncthreads();   // B1: all logits visible

    // ---- softmax over Y for head w (waves 0-7; mask-fill logits with 0);
    //      waves 8-15 proceed straight to GEMM -> softmax latency overlapped ----
    if (w < 8){
      float lgv[4];
      #pragma unroll
      for (int k = 0; k < 4; ++k){
        float v = coefT[w * 257 + (k << 6) + l];
        lgv[k] = mk[k] ? 0.f : v;
      }
      float mx = fmaxf(fmaxf(lgv[0], lgv[1]), fmaxf(lgv[2], lgv[3]));
      #pragma unroll
      for (int mm = 1; mm < 64; mm <<= 1) mx = fmaxf(mx, __shfl_xor(mx, mm));
      float e[4]; float sum = 0.f;
      #pragma unroll
      for (int k = 0; k < 4; ++k){ e[k] = __expf(lgv[k] - mx); sum += e[k]; }
      #pragma unroll
      for (int mm = 1; mm < 64; mm <<= 1) sum += __shfl_xor(sum, mm);
      float inv = 1.f / sum;
      #pragma unroll
      for (int k = 0; k < 4; ++k) coefT[w * 257 + (k << 6) + l] = e[k] * inv;
    }

    // ---- main GEMM: acc[nt], rows w*16+lg*4+r, col nt*16+lc ----
    f32x4 acc[16];
    #pragma unroll
    for (int nt = 0; nt < 16; ++nt) acc[nt] = (f32x4){0.f,0.f,0.f,0.f};

    #pragma unroll
    for (int nt = 0; nt < 16; ++nt){
      #pragma unroll
      for (int kk = 0; kk < 4; ++kk){
        f16x8 b = *(const f16x8*)(w1f + ((nt * 4 + kk) * 64 + l) * 8);
        acc[nt] = mfma16(ah[kk], b, acc[nt]);
      }
    }

    // ---- hid = acc + b1; LN stats (butterfly over lc bits 1,2,4,8) ----
    float s[4] = {0.f,0.f,0.f,0.f}, q[4] = {0.f,0.f,0.f,0.f};
    #pragma unroll
    for (int nt = 0; nt < 16; ++nt){
      float bv = ldsB1[nt * 16 + lc];
      #pragma unroll
      for (int r = 0; r < 4; ++r){
        float v = acc[nt][r] + bv;
        acc[nt][r] = v;
        s[r] += v;
        q[r] = fmaf(v, v, q[r]);
      }
    }
    #pragma unroll
    for (int mm = 1; mm <= 8; mm <<= 1){
      #pragma unroll
      for (int r = 0; r < 4; ++r){
        s[r] += __shfl_xor(s[r], mm);
        q[r] += __shfl_xor(q[r], mm);
      }
    }
    float mu[4], rstd[4];
    #pragma unroll
    for (int r = 0; r < 4; ++r){
      float m = s[r] * (1.f / 256.f);
      float var = q[r] * (1.f / 256.f) - m * m;
      mu[r] = m;
      rstd[r] = rsqrtf(fmaxf(var, 0.f) + 1e-5f);
    }
    __syncthreads();   // B2: softmax coefs visible (hidden under GEMM+stats)

    // ---- contraction: partial[col] = sum_{rows of wave} c*rstd*(hid - mu) ----
    #pragma unroll
    for (int h = 0; h < 8; ++h){
      float c2[4];
      float Dl = 0.f;
      #pragma unroll
      for (int r = 0; r < 4; ++r){
        float c = coefT[h * 257 + (w << 4) + (lg << 2) + r];
        float v = c * rstd[r];
        c2[r] = v;
        Dl = fmaf(v, mu[r], Dl);
      }
      #pragma unroll
      for (int t = 0; t < 2; ++t){
        int nt = h * 2 + t;               // cols nt*16+lc belong to head nt>>1 == h
        float p = -Dl;
        #pragma unroll
        for (int r = 0; r < 4; ++r) p = fmaf(c2[r], acc[nt][r], p);
        p += __shfl_xor(p, 16);
        p += __shfl_xor(p, 32);
        if (lg == 0) outp[w * 256 + nt * 16 + lc] = p;
      }
    }
    __syncthreads();   // B3: outp partials visible

    // ---- cross-wave reduce (16 waves), apply gamma/beta, f32 store ----
    if (tid < 256){
      float S = 0.f;
      #pragma unroll
      for (int ww = 0; ww < 16; ++ww) S += outp[ww * 256 + tid];
      out[((size_t)x << 8) + tid] = fmaf(ldsG[tid], S, ldsBt[tid]);
    }
  }
}

extern "C" void kernel_launch(void* const* d_in, const int* in_sizes, int n_in,
                              void* d_out, int out_size, void* d_ws, size_t ws_size,
                              hipStream_t stream){
  (void)in_sizes; (void)n_in; (void)out_size; (void)d_ws; (void)ws_size;
  const float* xy    = (const float*)d_in[0];
  const int*   mask  = (const int*)d_in[1];
  const float* W1    = (const float*)d_in[2];
  const float* b1    = (const float*)d_in[3];
  const float* gamma = (const float*)d_in[4];
  const float* beta  = (const float*)d_in[5];
  const float* W2    = (const float*)d_in[6];
  const float* b2    = (const float*)d_in[7];

  hipFuncSetAttribute((const void*)attn_main,
                      hipFuncAttributeMaxDynamicSharedMemorySize, (int)LDS_BYTES);
  attn_main<<<NBLK, 1024, LDS_BYTES, stream>>>(xy, mask, W1, b1, gamma, beta, W2, b2,
                                               (float*)d_out);
}